// Round 10
// baseline (213.792 us; speedup 1.0000x reference)
//
#include <hip/hip_runtime.h>
#include <hip/hip_bf16.h>

// NT-Xent, BATCH=4096, N=8192, D=512, TEMP=0.1 — MX-fp8 (e4m3, unit scales)
// Round 10: mfma_scale_f32_16x16x128_f8f6f4 (16-row fragment shape = r7's
// verified conflict-free LDS read pattern), 128x128 tile, BK=128, 512 thr,
// per-wave 64x32, 64 KB LDS, 2 blocks/CU.
// loss = mean_i [ logsumexp_{j!=i} sim[i,j] - sim[i,partner(i)] ]
// acc  = mean_i [ sim[i,partner(i)] >= max_{j!=i,partner} sim[i,j] ]
// sim = (msg_n . img_n^T)/TEMP, 10x folded into msg side before fp8 cast.

#define NROWS 8192
#define BATCHD 4096
#define DIM 512
#define BM 128
#define BN 128
#define BK 128
#define NSTEP (DIM / BK)   // 4 K-steps
#define SHIFT 10.0f

typedef int i32x8 __attribute__((ext_vector_type(8)));
typedef float f32x4 __attribute__((ext_vector_type(4)));

#define GLDS(g, l)                                                             \
    __builtin_amdgcn_global_load_lds(                                          \
        (const __attribute__((address_space(1))) void*)(g),                    \
        (__attribute__((address_space(3))) void*)(l), 16, 0, 0)

__device__ __forceinline__ unsigned f2u_ord(float f) {
    unsigned u = __float_as_uint(f);
    return (u & 0x80000000u) ? ~u : (u | 0x80000000u);
}
__device__ __forceinline__ float u2f_ord(unsigned e) {
    return (e & 0x80000000u) ? __uint_as_float(e & 0x7fffffffu) : __uint_as_float(~e);
}

// blocks 0..NROWS-1: msg (x10); NROWS..2*NROWS-1: img (x1).
// First 128 blocks also zero rowsum/rowmax/accum.
__global__ __launch_bounds__(64) void normalize_fp8_both(const float* __restrict__ msg,
                                                         const float* __restrict__ img,
                                                         unsigned char* __restrict__ mnb,
                                                         unsigned char* __restrict__ imb,
                                                         float* __restrict__ rowsum,
                                                         unsigned* __restrict__ rowmax,
                                                         float* __restrict__ accum) {
    if (blockIdx.x < 128) {
        const int i = blockIdx.x * 64 + threadIdx.x;
        rowsum[i] = 0.f;
        rowmax[i] = 0u;  // encodes "most negative"
        if (i < 2) accum[i] = 0.f;
    }
    int row = blockIdx.x;
    const float* in;
    unsigned char* out;
    float scale;
    if (row < NROWS) { in = msg; out = mnb; scale = 10.0f; }
    else { row -= NROWS; in = img; out = imb; scale = 1.0f; }
    const int lane = threadIdx.x;
    const float* src = in + (size_t)row * DIM + lane * 8;
    float4 v0 = *(const float4*)(src);
    float4 v1 = *(const float4*)(src + 4);
    float ss = v0.x*v0.x + v0.y*v0.y + v0.z*v0.z + v0.w*v0.w
             + v1.x*v1.x + v1.y*v1.y + v1.z*v1.z + v1.w*v1.w;
    #pragma unroll
    for (int off = 1; off < 64; off <<= 1) ss += __shfl_xor(ss, off);
    const float inv = scale / fmaxf(sqrtf(ss), 1e-8f);
    int w0 = __builtin_amdgcn_cvt_pk_fp8_f32(v0.x * inv, v0.y * inv, 0, false);
    w0 = __builtin_amdgcn_cvt_pk_fp8_f32(v0.z * inv, v0.w * inv, w0, true);
    int w1 = __builtin_amdgcn_cvt_pk_fp8_f32(v1.x * inv, v1.y * inv, 0, false);
    w1 = __builtin_amdgcn_cvt_pk_fp8_f32(v1.z * inv, v1.w * inv, w1, true);
    *(int2*)(out + (size_t)row * DIM + lane * 8) = make_int2(w0, w1);
}

// A = msg_n*10 (fp8), B = img_n (fp8); row-major [8192][512] bytes.
// 128x128 tile, 8 waves (2M x 4N, per-wave 64x32 as 4m x 2n of 16x16), BK=128.
// LDS per buffer: [128 rows][8 chunks of 16B]; chunk-slot p of row r holds
// logical chunk p ^ (r&7); linear GLDS dest, pre-swizzled global source.
// Fragment read: lane(r16,g) reads chunks {2g,2g+1} of row -> slots ^ (r16&7),
// 16 rows x 4 g-groups per read = r7's measured-0-conflict shape.
__global__ __launch_bounds__(512, 4) void simloss_mfma(const unsigned char* __restrict__ A,
                                                       const unsigned char* __restrict__ B,
                                                       float* __restrict__ rowsum,
                                                       unsigned* __restrict__ rowmax,
                                                       float* __restrict__ rowpos) {
    __shared__ __attribute__((aligned(16))) unsigned char As[2][BM * BK];  // 2x16 KB
    __shared__ __attribute__((aligned(16))) unsigned char Bs[2][BN * BK];  // 2x16 KB

    const int tid = threadIdx.x;
    const int lane = tid & 63;
    const int r16 = lane & 15;
    const int g = lane >> 4;     // k-group: 32 bytes each
    const int wid = tid >> 6;
    const int wr = wid >> 2;     // 0..1  (M waves, 64 rows each)
    const int wc = wid & 3;      // 0..3  (N waves, 32 cols each)

    // XCD stripes, bx-major traversal (by fastest): 4096 blocks = 64 by x 64 bx.
    const int bid = blockIdx.x;
    const int xcd = bid & 7;
    const int l = bid >> 3;          // 0..511
    const int by = xcd * 8 + (l & 7);
    const int bx = l >> 3;           // 0..63
    const int rowBase = by * BM;
    const int colBase = bx * BN;

    // staging: slot s in [0,1024): row = s>>3, slot-chunk = s&7,
    // fetch logical chunk (s&7) ^ ((s>>3)&7)  [inverse of read swizzle].
    // Thread stages slots {tid, tid+512} for A and B (4 GLDS per step).
    const int sA0 = tid, sA1 = tid + 512;
    const int r0 = sA0 >> 3, r1 = sA1 >> 3;
    const int c0 = (sA0 & 7) ^ (r0 & 7);
    const int c1 = (sA1 & 7) ^ (r1 & 7);
    const unsigned char* gA0 = A + (size_t)(rowBase + r0) * DIM + c0 * 16;
    const unsigned char* gA1 = A + (size_t)(rowBase + r1) * DIM + c1 * 16;
    const unsigned char* gB0 = B + (size_t)(colBase + r0) * DIM + c0 * 16;
    const unsigned char* gB1 = B + (size_t)(colBase + r1) * DIM + c1 * 16;

#define STAGE(b, koff)                                   \
    do {                                                 \
        GLDS(gA0 + (koff), &As[b][tid * 16]);            \
        GLDS(gA1 + (koff), &As[b][8192 + tid * 16]);     \
        GLDS(gB0 + (koff), &Bs[b][tid * 16]);            \
        GLDS(gB1 + (koff), &Bs[b][8192 + tid * 16]);     \
    } while (0)

    // fragment read base (bytes): row*128 + ((2g)^(row&7))*16; second chunk
    // slot = first ^ 1 -> addr ^ 16.  row&7 == r16&7 (m*16, w*32/64 = 0 mod 8).
    const int swz = r16 & 7;
    const int aBase0 = (wr * 64 + r16) * BK + (((g << 1) ^ swz) << 4);
    const int bBase0 = (wc * 32 + r16) * BK + (((g << 1) ^ swz) << 4);

    f32x4 acc[4][2] = {};

#define VMCNT(n) asm volatile("s_waitcnt vmcnt(" #n ")" ::: "memory")
#define BAR() __builtin_amdgcn_s_barrier()

    // prologue: stage tile 0
    STAGE(0, 0);

    #pragma unroll
    for (int t = 0; t < NSTEP; ++t) {
        const int b = t & 1;
        if (t < NSTEP - 1) {
            STAGE(b ^ 1, (t + 1) * BK);  // next tile's 4 GLDS in flight
            VMCNT(4);                    // tile t's 4 GLDS landed
        } else {
            VMCNT(0);
        }
        BAR();
        i32x8 af[4], bf[2];
        #pragma unroll
        for (int m = 0; m < 4; ++m) {
            const int ad = aBase0 + m * 16 * BK;
            *(uint4*)&af[m] = *(const uint4*)&As[b][ad];
            *((uint4*)&af[m] + 1) = *(const uint4*)&As[b][ad ^ 16];
        }
        #pragma unroll
        for (int n = 0; n < 2; ++n) {
            const int bd = bBase0 + n * 16 * BK;
            *(uint4*)&bf[n] = *(const uint4*)&Bs[b][bd];
            *((uint4*)&bf[n] + 1) = *(const uint4*)&Bs[b][bd ^ 16];
        }
        __builtin_amdgcn_s_setprio(1);
        #pragma unroll
        for (int m = 0; m < 4; ++m)
            #pragma unroll
            for (int n = 0; n < 2; ++n)
                // cbsz=0 (A=e4m3), blgp=0 (B=e4m3); unit e8m0 scales (0x7f=2^0)
                acc[m][n] = __builtin_amdgcn_mfma_scale_f32_16x16x128_f8f6f4(
                    af[m], bf[n], acc[m][n], 0, 0, 0, 0x7f7f7f7f, 0, 0x7f7f7f7f);
        __builtin_amdgcn_s_setprio(0);
        BAR();  // all waves done reading buf b before it is restaged
    }

    // ---- fused epilogue ----
    // 16x16 C/D layout [m89]: col = lane&15 (r16), row = g*4 + reg
    __syncthreads();
    float* ssum = (float*)&As[0][0];  // 128*4 floats
    float* smx = ssum + 512;          // 128*4 floats
    const int baseRow = rowBase + wr * 64 + g * 4;
    const int baseCol = colBase + wc * 32 + r16;
    #pragma unroll
    for (int m = 0; m < 4; ++m) {
        #pragma unroll
        for (int reg = 0; reg < 4; ++reg) {
            const int i = baseRow + m * 16 + reg;
            const int partner = i ^ BATCHD;
            float sum = 0.f, mx = -1e30f;
            #pragma unroll
            for (int n = 0; n < 2; ++n) {
                const int j = baseCol + n * 16;
                const float s = acc[m][n][reg];
                const bool isDiag = (j == i);
                const bool isPos = (j == partner);
                float e = __expf(s - SHIFT);
                if (isDiag) e = 0.f;
                sum += e;
                if (!isDiag && !isPos) mx = fmaxf(mx, s);
                if (isPos) rowpos[i] = s;  // exactly one writer grid-wide
            }
            // reduce across the 16 r16-lanes of this g-group
            #pragma unroll
            for (int off = 1; off < 16; off <<= 1) {
                sum += __shfl_xor(sum, off);
                mx = fmaxf(mx, __shfl_xor(mx, off));
            }
            if (r16 == 0) {
                const int rloc = wr * 64 + m * 16 + g * 4 + reg;
                ssum[rloc * 4 + wc] = sum;
                smx[rloc * 4 + wc] = mx;
            }
        }
    }
    __syncthreads();
    // combine the 4 column-waves' partials: one atomic pair per row per block
    if (tid < BM) {
        const float s = ssum[tid * 4 + 0] + ssum[tid * 4 + 1] +
                        ssum[tid * 4 + 2] + ssum[tid * 4 + 3];
        const float mx = fmaxf(fmaxf(smx[tid * 4 + 0], smx[tid * 4 + 1]),
                               fmaxf(smx[tid * 4 + 2], smx[tid * 4 + 3]));
        const int i = rowBase + tid;
        atomicAdd(&rowsum[i], s);
        atomicMax(&rowmax[i], f2u_ord(mx));
    }
#undef STAGE
#undef VMCNT
#undef BAR
}

// 32 blocks x 256 threads: one row per thread, block-reduce, atomic combine.
__global__ __launch_bounds__(256) void finalize_partial(const float* __restrict__ rowsum,
                                                        const unsigned* __restrict__ rowmax,
                                                        const float* __restrict__ rowpos,
                                                        float* __restrict__ accum) {
    const int tid = threadIdx.x;
    const int i = blockIdx.x * 256 + tid;
    const float lse = SHIFT + logf(rowsum[i]);
    const float pos = rowpos[i];
    float lossAcc = lse - pos;
    float hitAcc = (pos >= u2f_ord(rowmax[i])) ? 1.f : 0.f;
    __shared__ float sl[256], sa[256];
    sl[tid] = lossAcc; sa[tid] = hitAcc;
    __syncthreads();
    for (int s = 128; s > 0; s >>= 1) {
        if (tid < s) { sl[tid] += sl[tid + s]; sa[tid] += sa[tid + s]; }
        __syncthreads();
    }
    if (tid == 0) {
        atomicAdd(&accum[0], sl[0]);
        atomicAdd(&accum[1], sa[0]);
    }
}

__global__ void finalize_write(const float* __restrict__ accum, float* __restrict__ out) {
    if (threadIdx.x == 0) {
        out[0] = accum[0] / (float)NROWS;
        out[1] = accum[1] / (float)NROWS;
    }
}

extern "C" void kernel_launch(void* const* d_in, const int* in_sizes, int n_in,
                              void* d_out, int out_size, void* d_ws, size_t ws_size,
                              hipStream_t stream) {
    const float* msg = (const float*)d_in[0];
    const float* img = (const float*)d_in[1];
    float* out = (float*)d_out;

    char* ws = (char*)d_ws;
    const size_t matBytes = (size_t)NROWS * DIM;  // 4 MB (fp8)
    unsigned char* mnb = (unsigned char*)ws;
    unsigned char* imb = (unsigned char*)(ws + matBytes);
    float* rowsum = (float*)(ws + 2 * matBytes);
    unsigned* rowmax = (unsigned*)(ws + 2 * matBytes + NROWS * sizeof(float));
    float* rowpos = (float*)(ws + 2 * matBytes + 2 * NROWS * sizeof(float));
    float* accum = (float*)(ws + 2 * matBytes + 3 * NROWS * sizeof(float));

    normalize_fp8_both<<<2 * NROWS, 64, 0, stream>>>(msg, img, mnb, imb,
                                                     rowsum, rowmax, accum);

    simloss_mfma<<<(NROWS / BM) * (NROWS / BN), 512, 0, stream>>>(mnb, imb, rowsum,
                                                                  rowmax, rowpos);

    finalize_partial<<<NROWS / 256, 256, 0, stream>>>(rowsum, rowmax, rowpos, accum);
    finalize_write<<<1, 64, 0, stream>>>(accum, out);
}

// Round 11
// 115.246 us; speedup vs baseline: 1.8551x; 1.8551x over previous
//
#include <hip/hip_runtime.h>
#include <hip/hip_bf16.h>

// NT-Xent, BATCH=4096, N=8192, D=512, TEMP=0.1 — MX-fp8 (e4m3, unit scales)
// Round 11: r9's proven no-spill shape (32x32x64 scale-MFMA, per-wave 32x64,
// acc 32 regs, <=24 live frag regs) with BK=128 (2 sequential K=64 halves)
// -> 4 K-steps/block, 32 total step-slots (vs r9's 64). 64 KB LDS, 2 blk/CU.
// loss = mean_i [ logsumexp_{j!=i} sim[i,j] - sim[i,partner(i)] ]
// acc  = mean_i [ sim[i,partner(i)] >= max_{j!=i,partner} sim[i,j] ]
// sim = (msg_n . img_n^T)/TEMP, 10x folded into msg side before fp8 cast.

#define NROWS 8192
#define BATCHD 4096
#define DIM 512
#define BM 128
#define BN 128
#define BK 128
#define NSTEP (DIM / BK)   // 4 K-steps
#define SHIFT 10.0f

typedef int i32x8 __attribute__((ext_vector_type(8)));
typedef float f32x16 __attribute__((ext_vector_type(16)));

#define GLDS(g, l)                                                             \
    __builtin_amdgcn_global_load_lds(                                          \
        (const __attribute__((address_space(1))) void*)(g),                    \
        (__attribute__((address_space(3))) void*)(l), 16, 0, 0)

__device__ __forceinline__ unsigned f2u_ord(float f) {
    unsigned u = __float_as_uint(f);
    return (u & 0x80000000u) ? ~u : (u | 0x80000000u);
}
__device__ __forceinline__ float u2f_ord(unsigned e) {
    return (e & 0x80000000u) ? __uint_as_float(e & 0x7fffffffu) : __uint_as_float(~e);
}

// blocks 0..NROWS-1: msg (x10); NROWS..2*NROWS-1: img (x1).
// First 128 blocks also zero rowsum/rowmax/accum.
__global__ __launch_bounds__(64) void normalize_fp8_both(const float* __restrict__ msg,
                                                         const float* __restrict__ img,
                                                         unsigned char* __restrict__ mnb,
                                                         unsigned char* __restrict__ imb,
                                                         float* __restrict__ rowsum,
                                                         unsigned* __restrict__ rowmax,
                                                         float* __restrict__ accum) {
    if (blockIdx.x < 128) {
        const int i = blockIdx.x * 64 + threadIdx.x;
        rowsum[i] = 0.f;
        rowmax[i] = 0u;  // encodes "most negative"
        if (i < 2) accum[i] = 0.f;
    }
    int row = blockIdx.x;
    const float* in;
    unsigned char* out;
    float scale;
    if (row < NROWS) { in = msg; out = mnb; scale = 10.0f; }
    else { row -= NROWS; in = img; out = imb; scale = 1.0f; }
    const int lane = threadIdx.x;
    const float* src = in + (size_t)row * DIM + lane * 8;
    float4 v0 = *(const float4*)(src);
    float4 v1 = *(const float4*)(src + 4);
    float ss = v0.x*v0.x + v0.y*v0.y + v0.z*v0.z + v0.w*v0.w
             + v1.x*v1.x + v1.y*v1.y + v1.z*v1.z + v1.w*v1.w;
    #pragma unroll
    for (int off = 1; off < 64; off <<= 1) ss += __shfl_xor(ss, off);
    const float inv = scale / fmaxf(sqrtf(ss), 1e-8f);
    int w0 = __builtin_amdgcn_cvt_pk_fp8_f32(v0.x * inv, v0.y * inv, 0, false);
    w0 = __builtin_amdgcn_cvt_pk_fp8_f32(v0.z * inv, v0.w * inv, w0, true);
    int w1 = __builtin_amdgcn_cvt_pk_fp8_f32(v1.x * inv, v1.y * inv, 0, false);
    w1 = __builtin_amdgcn_cvt_pk_fp8_f32(v1.z * inv, v1.w * inv, w1, true);
    *(int2*)(out + (size_t)row * DIM + lane * 8) = make_int2(w0, w1);
}

// A = msg_n*10 (fp8), B = img_n (fp8); row-major [8192][512] bytes.
// 128x128 tile, 8 waves (4M x 2N, per-wave 32x64 as 1x2 of 32x32), BK=128
// processed as two K=64 halves (keeps r9's register working set).
// LDS per buffer: [128 rows][8 chunks of 16B]; chunk-slot p of row r holds
// logical chunk p ^ (r&7); linear GLDS dest, pre-swizzled global source.
__global__ __launch_bounds__(512, 4) void simloss_mfma(const unsigned char* __restrict__ A,
                                                       const unsigned char* __restrict__ B,
                                                       float* __restrict__ rowsum,
                                                       unsigned* __restrict__ rowmax,
                                                       float* __restrict__ rowpos) {
    __shared__ __attribute__((aligned(16))) unsigned char As[2][BM * BK];  // 2x16 KB
    __shared__ __attribute__((aligned(16))) unsigned char Bs[2][BN * BK];  // 2x16 KB

    const int tid = threadIdx.x;
    const int lane = tid & 63;
    const int r32 = lane & 31;
    const int h = lane >> 5;     // k-sub-half within a K=64 half (32 B each)
    const int wid = tid >> 6;
    const int wr = wid >> 1;     // 0..3  (M waves, 32 rows each)
    const int wc = wid & 1;      // 0..1  (N waves, 64 cols each)

    // XCD stripes, bx-major traversal (by fastest): 4096 blocks = 64 by x 64 bx.
    const int bid = blockIdx.x;
    const int xcd = bid & 7;
    const int l = bid >> 3;          // 0..511
    const int by = xcd * 8 + (l & 7);
    const int bx = l >> 3;           // 0..63
    const int rowBase = by * BM;
    const int colBase = bx * BN;

    // staging: slot s in [0,1024) per matrix: row = s>>3, slot-chunk = s&7,
    // fetch logical chunk (s&7) ^ ((s>>3)&7)  [involution with read swizzle].
    // Thread stages slots {tid, tid+512} for A and for B (4 GLDS per step).
    const int s0 = tid, s1 = tid + 512;
    const int r0 = s0 >> 3, r1 = s1 >> 3;
    const int c0 = (s0 & 7) ^ (r0 & 7);
    const int c1 = (s1 & 7) ^ (r1 & 7);
    const unsigned char* gA0 = A + (size_t)(rowBase + r0) * DIM + c0 * 16;
    const unsigned char* gA1 = A + (size_t)(rowBase + r1) * DIM + c1 * 16;
    const unsigned char* gB0 = B + (size_t)(colBase + r0) * DIM + c0 * 16;
    const unsigned char* gB1 = B + (size_t)(colBase + r1) * DIM + c1 * 16;

#define STAGE(b, koff)                                  \
    do {                                                \
        GLDS(gA0 + (koff), &As[b][tid * 16]);           \
        GLDS(gA1 + (koff), &As[b][8192 + tid * 16]);    \
        GLDS(gB0 + (koff), &Bs[b][tid * 16]);           \
        GLDS(gB1 + (koff), &Bs[b][8192 + tid * 16]);    \
    } while (0)

    // fragment read base (bytes) for K-half kh: lane needs logical chunks
    // {kh*4 + 2h, kh*4 + 2h + 1} of its row; slot = chunk ^ (row&7);
    // pair differs in bit0 -> second addr = first ^ 16. row&7 == r32&7.
    const int swz = r32 & 7;
    const int aRow = (wr * 32 + r32) * BK;
    const int bRow0 = (wc * 64 + r32) * BK;

    f32x16 acc0 = {}, acc1 = {};

#define VMCNT(n) asm volatile("s_waitcnt vmcnt(" #n ")" ::: "memory")
#define BAR() __builtin_amdgcn_s_barrier()

    // prologue: stage tile 0
    STAGE(0, 0);

    for (int t = 0; t < NSTEP; ++t) {
        const int b = t & 1;
        if (t < NSTEP - 1) {
            STAGE(b ^ 1, (t + 1) * BK);  // next tile's 4 GLDS in flight
            VMCNT(4);                    // tile t's 4 GLDS landed
        } else {
            VMCNT(0);
        }
        BAR();
        #pragma unroll
        for (int kh = 0; kh < 2; ++kh) {
            const int aAddr = aRow + ((((kh << 2) + (h << 1)) ^ swz) << 4);
            const int bAddr = bRow0 + ((((kh << 2) + (h << 1)) ^ swz) << 4);
            i32x8 af, bf0, bf1;
            *(uint4*)&af = *(const uint4*)&As[b][aAddr];
            *((uint4*)&af + 1) = *(const uint4*)&As[b][aAddr ^ 16];
            *(uint4*)&bf0 = *(const uint4*)&Bs[b][bAddr];
            *((uint4*)&bf0 + 1) = *(const uint4*)&Bs[b][bAddr ^ 16];
            *(uint4*)&bf1 = *(const uint4*)&Bs[b][bAddr + 32 * BK];
            *((uint4*)&bf1 + 1) = *(const uint4*)&Bs[b][(bAddr + 32 * BK) ^ 16];
            __builtin_amdgcn_s_setprio(1);
            // cbsz=0 (A=e4m3), blgp=0 (B=e4m3); unit e8m0 scales (0x7f=2^0)
            acc0 = __builtin_amdgcn_mfma_scale_f32_32x32x64_f8f6f4(
                af, bf0, acc0, 0, 0, 0, 0x7f7f7f7f, 0, 0x7f7f7f7f);
            acc1 = __builtin_amdgcn_mfma_scale_f32_32x32x64_f8f6f4(
                af, bf1, acc1, 0, 0, 0, 0x7f7f7f7f, 0, 0x7f7f7f7f);
            __builtin_amdgcn_s_setprio(0);
        }
        BAR();  // all waves done reading buf b before it is restaged
    }

    // ---- fused epilogue ----
    // 32x32 C/D layout [m74/m101]: col = lane&31, row = (reg&3)+8*(reg>>2)+4*h
    __syncthreads();
    float* ssum = (float*)&As[0][0];  // 128*2 floats
    float* smx = ssum + 256;          // 128*2 floats
    const int baseRow = rowBase + wr * 32 + 4 * h;
    const int baseCol = colBase + wc * 64 + r32;
    #pragma unroll
    for (int reg = 0; reg < 16; ++reg) {
        const int rloc0 = (reg & 3) + 8 * (reg >> 2);
        const int i = baseRow + rloc0;
        const int partner = i ^ BATCHD;
        float sum = 0.f, mx = -1e30f;
        #pragma unroll
        for (int ns = 0; ns < 2; ++ns) {
            const int j = baseCol + ns * 32;
            const float s = (ns == 0) ? acc0[reg] : acc1[reg];
            const bool isDiag = (j == i);
            const bool isPos = (j == partner);
            float e = __expf(s - SHIFT);
            if (isDiag) e = 0.f;
            sum += e;
            if (!isDiag && !isPos) mx = fmaxf(mx, s);
            if (isPos) rowpos[i] = s;  // exactly one writer grid-wide
        }
        // reduce across the 32 lanes (cols) of this h-group
        #pragma unroll
        for (int off = 1; off < 32; off <<= 1) {
            sum += __shfl_xor(sum, off);
            mx = fmaxf(mx, __shfl_xor(mx, off));
        }
        if (r32 == 0) {
            const int rloc = wr * 32 + rloc0 + 4 * h;
            ssum[rloc * 2 + wc] = sum;
            smx[rloc * 2 + wc] = mx;
        }
    }
    __syncthreads();
    // combine the 2 column-waves' partials: one atomic pair per row per block
    if (tid < BM) {
        const float s = ssum[tid * 2 + 0] + ssum[tid * 2 + 1];
        const float mx = fmaxf(smx[tid * 2 + 0], smx[tid * 2 + 1]);
        const int i = rowBase + tid;
        atomicAdd(&rowsum[i], s);
        atomicMax(&rowmax[i], f2u_ord(mx));
    }
#undef STAGE
#undef VMCNT
#undef BAR
}

// 32 blocks x 256 threads: one row per thread, block-reduce, atomic combine.
__global__ __launch_bounds__(256) void finalize_partial(const float* __restrict__ rowsum,
                                                        const unsigned* __restrict__ rowmax,
                                                        const float* __restrict__ rowpos,
                                                        float* __restrict__ accum) {
    const int tid = threadIdx.x;
    const int i = blockIdx.x * 256 + tid;
    const float lse = SHIFT + logf(rowsum[i]);
    const float pos = rowpos[i];
    float lossAcc = lse - pos;
    float hitAcc = (pos >= u2f_ord(rowmax[i])) ? 1.f : 0.f;
    __shared__ float sl[256], sa[256];
    sl[tid] = lossAcc; sa[tid] = hitAcc;
    __syncthreads();
    for (int s = 128; s > 0; s >>= 1) {
        if (tid < s) { sl[tid] += sl[tid + s]; sa[tid] += sa[tid + s]; }
        __syncthreads();
    }
    if (tid == 0) {
        atomicAdd(&accum[0], sl[0]);
        atomicAdd(&accum[1], sa[0]);
    }
}

__global__ void finalize_write(const float* __restrict__ accum, float* __restrict__ out) {
    if (threadIdx.x == 0) {
        out[0] = accum[0] / (float)NROWS;
        out[1] = accum[1] / (float)NROWS;
    }
}

extern "C" void kernel_launch(void* const* d_in, const int* in_sizes, int n_in,
                              void* d_out, int out_size, void* d_ws, size_t ws_size,
                              hipStream_t stream) {
    const float* msg = (const float*)d_in[0];
    const float* img = (const float*)d_in[1];
    float* out = (float*)d_out;

    char* ws = (char*)d_ws;
    const size_t matBytes = (size_t)NROWS * DIM;  // 4 MB (fp8)
    unsigned char* mnb = (unsigned char*)ws;
    unsigned char* imb = (unsigned char*)(ws + matBytes);
    float* rowsum = (float*)(ws + 2 * matBytes);
    unsigned* rowmax = (unsigned*)(ws + 2 * matBytes + NROWS * sizeof(float));
    float* rowpos = (float*)(ws + 2 * matBytes + 2 * NROWS * sizeof(float));
    float* accum = (float*)(ws + 2 * matBytes + 3 * NROWS * sizeof(float));

    normalize_fp8_both<<<2 * NROWS, 64, 0, stream>>>(msg, img, mnb, imb,
                                                     rowsum, rowmax, accum);

    simloss_mfma<<<(NROWS / BM) * (NROWS / BN), 512, 0, stream>>>(mnb, imb, rowsum,
                                                                  rowmax, rowpos);

    finalize_partial<<<NROWS / 256, 256, 0, stream>>>(rowsum, rowmax, rowpos, accum);
    finalize_write<<<1, 64, 0, stream>>>(accum, out);
}

// Round 12
// 105.654 us; speedup vs baseline: 2.0235x; 1.0908x over previous
//
#include <hip/hip_runtime.h>
#include <hip/hip_bf16.h>

// NT-Xent, BATCH=4096, N=8192, D=512, TEMP=0.1 — bf16 MFMA.
// Round 12: r7 schedule, but 256-thread blocks (4 waves, 2x2 of 64x64),
// 128x128 tile, BK=32, 32 KB LDS dbuf, <=128 VGPR -> 4 blocks/CU.
// Mechanism: unsynchronized co-resident blocks hide each other's
// barrier/vmcnt stalls (occupancy was the only mover: 1blk->21%, 2blk->29%).
// loss = mean_i [ logsumexp_{j!=i} sim[i,j] - sim[i,partner(i)] ]
// acc  = mean_i [ sim[i,partner(i)] >= max_{j!=i,partner} sim[i,j] ]
// sim = (msg_n . img_n^T)/TEMP, 10x folded into msg side before bf16 cast.

#define NROWS 8192
#define BATCHD 4096
#define DIM 512
#define BM 128
#define BN 128
#define BK 32
#define NSTEP (DIM / BK)   // 16 K-steps
#define SHIFT 10.0f

typedef short bf16x8 __attribute__((ext_vector_type(8)));
typedef float f32x4 __attribute__((ext_vector_type(4)));

#define GLDS(g, l)                                                             \
    __builtin_amdgcn_global_load_lds(                                          \
        (const __attribute__((address_space(1))) void*)(g),                    \
        (__attribute__((address_space(3))) void*)(l), 16, 0, 0)

__device__ __forceinline__ unsigned f2u_ord(float f) {
    unsigned u = __float_as_uint(f);
    return (u & 0x80000000u) ? ~u : (u | 0x80000000u);
}
__device__ __forceinline__ float u2f_ord(unsigned e) {
    return (e & 0x80000000u) ? __uint_as_float(e & 0x7fffffffu) : __uint_as_float(~e);
}
__device__ __forceinline__ short f2bf(float f) {  // RNE f32 -> bf16 bits
    unsigned u = __float_as_uint(f);
    return (short)((u + 0x7fffu + ((u >> 16) & 1u)) >> 16);
}

// blocks 0..NROWS-1: msg (x10); NROWS..2*NROWS-1: img (x1).
// First 128 blocks also zero rowsum/rowmax/accum.
__global__ __launch_bounds__(64) void normalize_bf16_both(const float* __restrict__ msg,
                                                          const float* __restrict__ img,
                                                          short* __restrict__ mnb,
                                                          short* __restrict__ imb,
                                                          float* __restrict__ rowsum,
                                                          unsigned* __restrict__ rowmax,
                                                          float* __restrict__ accum) {
    if (blockIdx.x < 128) {
        const int i = blockIdx.x * 64 + threadIdx.x;
        rowsum[i] = 0.f;
        rowmax[i] = 0u;  // encodes "most negative"
        if (i < 2) accum[i] = 0.f;
    }
    int row = blockIdx.x;
    const float* in;
    short* out;
    float scale;
    if (row < NROWS) { in = msg; out = mnb; scale = 10.0f; }
    else { row -= NROWS; in = img; out = imb; scale = 1.0f; }
    const int lane = threadIdx.x;
    const float* src = in + (size_t)row * DIM + lane * 8;
    float4 v0 = *(const float4*)(src);
    float4 v1 = *(const float4*)(src + 4);
    float ss = v0.x*v0.x + v0.y*v0.y + v0.z*v0.z + v0.w*v0.w
             + v1.x*v1.x + v1.y*v1.y + v1.z*v1.z + v1.w*v1.w;
    #pragma unroll
    for (int off = 1; off < 64; off <<= 1) ss += __shfl_xor(ss, off);
    const float inv = scale / fmaxf(sqrtf(ss), 1e-8f);
    float vv[8] = {v0.x, v0.y, v0.z, v0.w, v1.x, v1.y, v1.z, v1.w};
    bf16x8 o;
    #pragma unroll
    for (int j = 0; j < 8; ++j) o[j] = f2bf(vv[j] * inv);
    *(bf16x8*)(out + (size_t)row * DIM + lane * 8) = o;
}

// A = msg_n*10 (bf16), B = img_n (bf16); row-major [8192][512].
// 128x128 tile, 4 waves (2M x 2N, per-wave 64x64), BK=32.
// LDS per buffer: [128 rows][4 chunks of 16B], chunk-slot p of row r holds
// logical chunk p ^ ((r>>1)&3) (verified 0-conflict); linear GLDS dest,
// pre-swizzled global source.
__global__ __launch_bounds__(256, 4) void simloss_mfma(const short* __restrict__ A,
                                                       const short* __restrict__ B,
                                                       float* __restrict__ rowsum,
                                                       unsigned* __restrict__ rowmax,
                                                       float* __restrict__ rowpos) {
    __shared__ short As[2][BM * BK];  // 2 x 8 KB
    __shared__ short Bs[2][BN * BK];  // 2 x 8 KB   -> 32 KB total

    const int tid = threadIdx.x;
    const int lane = tid & 63;
    const int g = lane >> 4;     // k-chunk 0..3
    const int r16 = lane & 15;
    const int wid = tid >> 6;
    const int wr = wid >> 1;     // 0..1  (M waves, 64 rows each)
    const int wc = wid & 1;      // 0..1  (N waves, 64 cols each)

    // XCD stripes, bx-major traversal (by fastest): 4096 blocks = 64 by x 64 bx.
    const int bid = blockIdx.x;
    const int xcd = bid & 7;
    const int l = bid >> 3;          // 0..511
    const int by = xcd * 8 + (l & 7);
    const int bx = l >> 3;           // 0..63
    const int rowBase = by * BM;
    const int colBase = bx * BN;

    // staging: slot s in [0,512) per matrix: row = s>>2, slot-chunk = s&2bits,
    // fetch logical chunk (s&3) ^ ((row>>1)&3)  [involution with read swizzle].
    // Thread stages slots {tid, tid+256} for A and for B (4 GLDS per step).
    const int s0 = tid, s1 = tid + 256;
    const int r0 = s0 >> 2, r1 = s1 >> 2;       // 0..63, 64..127
    const int c0 = (s0 & 3) ^ ((r0 >> 1) & 3);
    const int c1 = (s1 & 3) ^ ((r1 >> 1) & 3);
    const short* gA0 = A + (size_t)(rowBase + r0) * DIM + c0 * 8;
    const short* gA1 = A + (size_t)(rowBase + r1) * DIM + c1 * 8;
    const short* gB0 = B + (size_t)(colBase + r0) * DIM + c0 * 8;
    const short* gB1 = B + (size_t)(colBase + r1) * DIM + c1 * 8;

#define STAGE(b, koff)                                  \
    do {                                                \
        GLDS(gA0 + (koff), &As[b][tid * 8]);            \
        GLDS(gA1 + (koff), &As[b][2048 + tid * 8]);     \
        GLDS(gB0 + (koff), &Bs[b][tid * 8]);            \
        GLDS(gB1 + (koff), &Bs[b][2048 + tid * 8]);     \
    } while (0)

    // fragment read bases (shorts); same XOR on read side (r7-verified shape)
    const int swz = (r16 >> 1) & 3;
    const int aBase = (wr * 64 + r16) * BK + ((g ^ swz) * 8);
    const int bBase = (wc * 64 + r16) * BK + ((g ^ swz) * 8);

    f32x4 acc[4][4] = {};

#define VMCNT(n) asm volatile("s_waitcnt vmcnt(" #n ")" ::: "memory")
#define BAR() __builtin_amdgcn_s_barrier()

    // prologue: stage tile 0
    STAGE(0, 0);

    for (int t = 0; t < NSTEP; ++t) {
        const int b = t & 1;
        if (t < NSTEP - 1) {
            STAGE(b ^ 1, (t + 1) * BK);  // next tile's 4 GLDS in flight
            VMCNT(4);                    // tile t's 4 GLDS landed
        } else {
            VMCNT(0);
        }
        BAR();                           // buf b staged for all waves
        bf16x8 af[4], bfr[4];
        #pragma unroll
        for (int m = 0; m < 4; ++m)
            af[m] = *(const bf16x8*)&As[b][aBase + m * 16 * BK];
        #pragma unroll
        for (int n = 0; n < 4; ++n)
            bfr[n] = *(const bf16x8*)&Bs[b][bBase + n * 16 * BK];
        __builtin_amdgcn_s_setprio(1);
        #pragma unroll
        for (int m = 0; m < 4; ++m)
            #pragma unroll
            for (int n = 0; n < 4; ++n)
                acc[m][n] = __builtin_amdgcn_mfma_f32_16x16x32_bf16(
                    af[m], bfr[n], acc[m][n], 0, 0, 0);
        __builtin_amdgcn_s_setprio(0);
        BAR();  // all waves done reading buf b before it is restaged
    }

    // ---- fused epilogue ----
    // C/D layout: col = lane&15 (r16), row = g*4 + reg  [m89 verified]
    __syncthreads();
    float* ssum = (float*)&As[0][0];  // 128*2 floats
    float* smx = ssum + 256;          // 128*2 floats
    const int baseRow = rowBase + wr * 64 + g * 4;
    const int baseCol = colBase + wc * 64 + r16;
    #pragma unroll
    for (int m = 0; m < 4; ++m) {
        #pragma unroll
        for (int reg = 0; reg < 4; ++reg) {
            const int i = baseRow + m * 16 + reg;
            const int partner = i ^ BATCHD;
            float sum = 0.f, mx = -1e30f;
            #pragma unroll
            for (int n = 0; n < 4; ++n) {
                const int j = baseCol + n * 16;
                const float s = acc[m][n][reg];
                const bool isDiag = (j == i);
                const bool isPos = (j == partner);
                float e = __expf(s - SHIFT);
                if (isDiag) e = 0.f;
                sum += e;
                if (!isDiag && !isPos) mx = fmaxf(mx, s);
                if (isPos) rowpos[i] = s;  // exactly one writer grid-wide
            }
            #pragma unroll
            for (int off = 1; off < 16; off <<= 1) {
                sum += __shfl_xor(sum, off);
                mx = fmaxf(mx, __shfl_xor(mx, off));
            }
            if (r16 == 0) {
                const int rloc = wr * 64 + m * 16 + g * 4 + reg;
                ssum[rloc * 2 + wc] = sum;
                smx[rloc * 2 + wc] = mx;
            }
        }
    }
    __syncthreads();
    // combine the 2 column-waves' partials: one atomic pair per row per block
    if (tid < BM) {
        const float s = ssum[tid * 2 + 0] + ssum[tid * 2 + 1];
        const float mx = fmaxf(smx[tid * 2 + 0], smx[tid * 2 + 1]);
        const int i = rowBase + tid;
        atomicAdd(&rowsum[i], s);
        atomicMax(&rowmax[i], f2u_ord(mx));
    }
#undef STAGE
#undef VMCNT
#undef BAR
}

// 32 blocks x 256 threads: one row per thread, block-reduce, atomic combine.
__global__ __launch_bounds__(256) void finalize_partial(const float* __restrict__ rowsum,
                                                        const unsigned* __restrict__ rowmax,
                                                        const float* __restrict__ rowpos,
                                                        float* __restrict__ accum) {
    const int tid = threadIdx.x;
    const int i = blockIdx.x * 256 + tid;
    const float lse = SHIFT + logf(rowsum[i]);
    const float pos = rowpos[i];
    float lossAcc = lse - pos;
    float hitAcc = (pos >= u2f_ord(rowmax[i])) ? 1.f : 0.f;
    __shared__ float sl[256], sa[256];
    sl[tid] = lossAcc; sa[tid] = hitAcc;
    __syncthreads();
    for (int s = 128; s > 0; s >>= 1) {
        if (tid < s) { sl[tid] += sl[tid + s]; sa[tid] += sa[tid + s]; }
        __syncthreads();
    }
    if (tid == 0) {
        atomicAdd(&accum[0], sl[0]);
        atomicAdd(&accum[1], sa[0]);
    }
}

__global__ void finalize_write(const float* __restrict__ accum, float* __restrict__ out) {
    if (threadIdx.x == 0) {
        out[0] = accum[0] / (float)NROWS;
        out[1] = accum[1] / (float)NROWS;
    }
}

extern "C" void kernel_launch(void* const* d_in, const int* in_sizes, int n_in,
                              void* d_out, int out_size, void* d_ws, size_t ws_size,
                              hipStream_t stream) {
    const float* msg = (const float*)d_in[0];
    const float* img = (const float*)d_in[1];
    float* out = (float*)d_out;

    char* ws = (char*)d_ws;
    const size_t matBytes = (size_t)NROWS * DIM * sizeof(short);  // 8 MB
    short* mnb = (short*)ws;
    short* imb = (short*)(ws + matBytes);
    float* rowsum = (float*)(ws + 2 * matBytes);
    unsigned* rowmax = (unsigned*)(ws + 2 * matBytes + NROWS * sizeof(float));
    float* rowpos = (float*)(ws + 2 * matBytes + 2 * NROWS * sizeof(float));
    float* accum = (float*)(ws + 2 * matBytes + 3 * NROWS * sizeof(float));

    normalize_bf16_both<<<2 * NROWS, 64, 0, stream>>>(msg, img, mnb, imb,
                                                      rowsum, rowmax, accum);

    simloss_mfma<<<(NROWS / BM) * (NROWS / BN), 256, 0, stream>>>(mnb, imb, rowsum,
                                                                  rowmax, rowpos);

    finalize_partial<<<NROWS / 256, 256, 0, stream>>>(rowsum, rowmax, rowpos, accum);
    finalize_write<<<1, 64, 0, stream>>>(accum, out);
}